// Round 6
// baseline (1918.882 us; speedup 1.0000x reference)
//
#include <hip/hip_runtime.h>
#include <hip/hip_bf16.h>

// ============================================================================
// RecurrentDecoder v6: 66-block persistent kernel, NO grid barriers in loop.
// Producer/consumer counters (system-scope, sc0sc1) + depth-4 rings for h/ctx.
//  - att blocks 0..31 (one per b): ali slice LDS-resident in [e][t] stride-260
//    layout (b64 LDS reads, conflict-free), W_att in VGPRs. Computes ctx(s).
//  - GRU blocks 32..63 (16-col D-slice each): weights VGPR-resident.
//    gh(s)+gi_dec(s) overlap att; then wait ctx(s) -> gi_ctx -> pointwise ->
//    h(s+1) slice -> hdone.
//  - mel blocks 64..65: wait h(tau+1) -> mel/gate(tau) -> meldone (guards
//    ring overwrite, depth-4 so never on critical path).
// Cross-block data/flags: __hip_atomic_* SYSTEM scope (sc0 sc1 => coherence
// point, no L2-invalidating fences). One fence-barrier only after P0.
// ============================================================================

#define LOG2E 1.4426950408889634f
#define FLAGS_MAGIC 0x13572468u
#define SMEM_BYTES 146432

typedef __attribute__((ext_vector_type(8))) short bf8;
typedef __attribute__((ext_vector_type(4))) float f32x4;
typedef unsigned long long ull;

#define EX2(x) exp2f(x)
#define MFMA16(a, b, c) __builtin_amdgcn_mfma_f32_16x16x32_bf16(a, b, c, 0, 0, 0)

struct Params {
  const float* dec;    // [64][32][256]
  const float* ali;    // [256][32][256]
  const float* watt;   // [256][512]
  const float* wih;    // [1536][512]
  const float* whh;    // [1536][512]
  const float* wmel;   // [80][768]
  const float* bmel;   // [80]
  const float* wgate;  // [768]
  const float* bgate;  // [1]
  float* out;          // mel 32*80*64 then gate 32*64
  unsigned* bar;       // [0]=magic [16]=p0cnt [32+16i]=hdone[i]
                       // [544+16i]=ctxdone[i] [1056+16m]=meldone[m]
  __hip_bfloat16* wihb;    // [1536][512]
  __hip_bfloat16* whhb;    // [1536][512]
  __hip_bfloat16* wmelgb;  // [96][768]
  __hip_bfloat16* seqb;    // [64][32][256]
  __hip_bfloat16* hbf;     // ring [4][32][512]
  __hip_bfloat16* ctxb;    // ring [4][32][256]
  unsigned* wattp;         // [256][256] packed bf16 pairs of W_att^T
};

__device__ __forceinline__ bf8 ldfrag(const __hip_bfloat16* p) {
  return *(const bf8*)p;
}
__device__ __forceinline__ float sigm(float x) {
  return 1.0f / (1.0f + EX2(-x * LOG2E));
}
__device__ __forceinline__ float tanhfast(float x) {
  x = fminf(fmaxf(x, -15.0f), 15.0f);
  float e = EX2(x * (2.0f * LOG2E));
  return (e - 1.0f) / (e + 1.0f);
}
__device__ __forceinline__ float btof(unsigned v) {
  return __uint_as_float(v << 16);
}
__device__ __forceinline__ unsigned short f2bfbits(float x) {
  __hip_bfloat16 h = __float2bfloat16(x);
  return *(unsigned short*)&h;
}
// --- system-scope (sc0 sc1) coherent accessors: no fences needed ---
__device__ __forceinline__ unsigned sysld32(const unsigned* p) {
  return __hip_atomic_load(p, __ATOMIC_RELAXED, __HIP_MEMORY_SCOPE_SYSTEM);
}
__device__ __forceinline__ ull sysld64(const ull* p) {
  return __hip_atomic_load(p, __ATOMIC_RELAXED, __HIP_MEMORY_SCOPE_SYSTEM);
}
__device__ __forceinline__ void sysst32(unsigned* p, unsigned v) {
  __hip_atomic_store(p, v, __ATOMIC_RELAXED, __HIP_MEMORY_SCOPE_SYSTEM);
}
__device__ __forceinline__ void sysst64(ull* p, ull v) {
  __hip_atomic_store(p, v, __ATOMIC_RELAXED, __HIP_MEMORY_SCOPE_SYSTEM);
}
__device__ __forceinline__ bf8 ldfrag_sys(const __hip_bfloat16* p) {
  union { ull u[2]; bf8 v; } x;
  x.u[0] = sysld64((const ull*)p);
  x.u[1] = sysld64((const ull*)p + 1);
  return x.v;
}
__device__ __forceinline__ void waitge(unsigned* w, unsigned tgt) {
  while (sysld32(w) < tgt) __builtin_amdgcn_s_sleep(1);
}

// One-time P0 barrier (66 blocks), with agent fences for the normal-store
// converted-weight handoff (pattern proven correct in v4/v5).
__device__ __forceinline__ void p0bar(unsigned* bar) {
  __syncthreads();
  if (threadIdx.x == 0) {
    __builtin_amdgcn_fence(__ATOMIC_RELEASE, "agent");
    __hip_atomic_fetch_add(bar + 16, 1u, __ATOMIC_RELAXED, __HIP_MEMORY_SCOPE_SYSTEM);
    while (sysld32(bar + 16) < 66u) __builtin_amdgcn_s_sleep(1);
    __builtin_amdgcn_fence(__ATOMIC_ACQUIRE, "agent");
  }
  __syncthreads();
}

// P0 conversion work for blocks 32..65 (wid in [0, 34*512))
__device__ __forceinline__ void p0a_worker(const Params& p, int wid) {
  for (int i = wid; i < 2252800; i += 17408) {
    if (i < 786432) {
      p.wihb[i] = __float2bfloat16(p.wih[i]);
    } else if (i < 1572864) {
      int j = i - 786432;
      p.whhb[j] = __float2bfloat16(p.whh[j]);
    } else if (i < 2097152) {
      int j = i - 1572864;
      int s = j >> 13;
      p.seqb[j] = (s == 0) ? __float2bfloat16(0.0f) : __float2bfloat16(p.dec[j - 8192]);
    } else if (i < 2170880) {
      int j = i - 2097152;
      int r = j / 768, c = j - r * 768;
      float v = (r < 80) ? p.wmel[j] : ((r == 80) ? p.wgate[c] : 0.0f);
      p.wmelgb[j] = __float2bfloat16(v);
    } else if (i < 2236416) {
      int j = i - 2170880;
      int kp = j >> 8, e = j & 255;
      unsigned lo = f2bfbits(p.watt[e * 512 + 2 * kp]);
      unsigned hi = f2bfbits(p.watt[e * 512 + 2 * kp + 1]);
      p.wattp[j] = lo | (hi << 16);
    } else {
      int j = i - 2236416;
      p.hbf[j] = __float2bfloat16(0.0f);  // h ring slot 0 = h(0) = 0
    }
  }
}

__global__ void __launch_bounds__(512, 1) rdec_kernel(Params p) {
  const int tid = threadIdx.x;
  const int bid = blockIdx.x;
  extern __shared__ char smem[];
  unsigned* hdone = p.bar + 32;     // stride 16
  unsigned* ctxdone = p.bar + 544;  // stride 16
  unsigned* meldone = p.bar + 1056; // stride 16

  // ---- flag init (ws poisoned 0xAA each launch): block0 zeroes, sets magic
  if (bid == 0) {
    for (int i = 1 + tid; i < 1100; i += 512)
      sysst32(p.bar + i, 0u);
    __syncthreads();
    if (tid == 0) sysst32(p.bar, FLAGS_MAGIC);
  }

  if (bid < 32) {
    // ============================ ATT path ============================
    const int b = bid;
    unsigned short* alds = (unsigned short*)smem;     // [256][260] bf16 [e][t]
    float* shh = (float*)(smem + 256 * 260 * 2);      // 512
    float* shp = shh + 512;                           // 256
    float* shr = shp + 256;                           // 256
    float* shtw = shr + 256;                          // 256
    float* pA = shtw + 256;                           // 512
    float* pB = pA + 512;
    float* pC = pB + 512;
    float* pD = pC + 512;
    unsigned short* pc16 = (unsigned short*)pC;       // staging (reuse)
    const int e = tid & 255, th = tid >> 8;

    // P0: ali -> LDS bf16 in [e][t] layout (stride 260, conflict-free b64)
    for (int i = tid; i < 65536; i += 512) {
      int t = i >> 8, ee = i & 255;
      alds[ee * 260 + t] = f2bfbits(p.ali[t * 8192 + b * 256 + ee]);
    }
    if (tid == 0) waitge(p.bar, FLAGS_MAGIC);  // exact-match poll below magic
    while (sysld32(p.bar) != FLAGS_MAGIC) { if (tid == 0) __builtin_amdgcn_s_sleep(1); break; }
    // (all threads confirm magic before p0bar's counter use)
    if (sysld32(p.bar) != FLAGS_MAGIC) { while (sysld32(p.bar) != FLAGS_MAGIC) __builtin_amdgcn_s_sleep(1); }
    p0bar(p.bar);
    // resident W_att^T slice
    unsigned wr[128];
#pragma unroll
    for (int i = 0; i < 128; ++i) wr[i] = p.wattp[(th * 128 + i) * 256 + e];

    for (int s = 0; s < 64; ++s) {
      // top-of-step polls: h(s) ready; mel far enough behind to reuse ctx slot
      if (tid < 32) waitge(hdone + tid * 16, (unsigned)s);
      else if (tid < 34) waitge(meldone + (tid - 32) * 16, (s >= 4) ? (unsigned)(s - 3) : 0u);
      __syncthreads();
      // load h(s)[b,:] bf16 coherent -> shh fp32
      if (tid < 128) {
        ull w = sysld64((const ull*)(p.hbf + (s & 3) * 16384 + b * 512) + tid);
        shh[tid * 4 + 0] = btof((unsigned)(w & 0xffff));
        shh[tid * 4 + 1] = btof((unsigned)((w >> 16) & 0xffff));
        shh[tid * 4 + 2] = btof((unsigned)((w >> 32) & 0xffff));
        shh[tid * 4 + 3] = btof((unsigned)((w >> 48) & 0xffff));
      }
      __syncthreads();
      // proj partial (k-split by th) from resident registers
      {
        float acc = 0.f;
        const float2* h2 = (const float2*)shh;
#pragma unroll
        for (int i = 0; i < 128; ++i) {
          unsigned w = wr[i];
          float2 hv = h2[th * 128 + i];
          acc = fmaf(__uint_as_float(w << 16), hv.x, acc);
          acc = fmaf(__uint_as_float(w & 0xffff0000u), hv.y, acc);
        }
        pA[th * 256 + e] = acc;
      }
      __syncthreads();
      const float p2 = (pA[e] + pA[256 + e]) * LOG2E;
      if (tid < 256) shp[e] = p2;
      // denominator partial (t-split by th): b64 LDS reads
      {
        const ushort4* row = (const ushort4*)(alds + e * 260 + th * 128);
        float d0 = 0.f;
#pragma unroll 8
        for (int q = 0; q < 32; ++q) {
          ushort4 v = row[q];
          d0 += EX2(btof(v.x) * p2);
          d0 += EX2(btof(v.y) * p2);
          d0 += EX2(btof(v.z) * p2);
          d0 += EX2(btof(v.w) * p2);
        }
        pB[th * 256 + e] = d0;
      }
      __syncthreads();
      if (tid < 256) shr[e] = 1.0f / (pB[e] + pB[256 + e]);
      __syncthreads();
      // tw partial (e-split by th): lane-contiguous u16 reads
      {
        const int t = tid & 255;
        float acc = 0.f;
        const int e0 = th * 128;
#pragma unroll 8
        for (int ee = e0; ee < e0 + 128; ++ee) {
          acc += EX2(btof(alds[ee * 260 + t]) * shp[ee]) * shr[ee];
        }
        pC[th * 256 + t] = acc;
      }
      __syncthreads();
      if (tid < 256) shtw[tid] = pC[tid] + pC[256 + tid];
      __syncthreads();
      // ctx partial (t-split by th): b64 LDS reads
      {
        const ushort4* row = (const ushort4*)(alds + e * 260 + th * 128);
        const float* twp = shtw + th * 128;
        float c0 = 0.f;
#pragma unroll 8
        for (int q = 0; q < 32; ++q) {
          ushort4 v = row[q];
          c0 += twp[q * 4 + 0] * btof(v.x);
          c0 += twp[q * 4 + 1] * btof(v.y);
          c0 += twp[q * 4 + 2] * btof(v.z);
          c0 += twp[q * 4 + 3] * btof(v.w);
        }
        pD[th * 256 + e] = c0;
      }
      __syncthreads();
      if (tid < 256) pc16[e] = f2bfbits(pD[e] + pD[256 + e]);
      __syncthreads();
      if (tid < 64)
        sysst64((ull*)(p.ctxb + (s & 3) * 8192 + b * 256) + tid, ((const ull*)pc16)[tid]);
      __syncthreads();  // drains the coherent stores (vmcnt)
      if (tid == 0) sysst32(ctxdone + b * 16, (unsigned)(s + 1));
    }
  } else if (bid < 64) {
    // ============================ GRU path ============================
    const int dt = bid - 32;
    const int wv = tid >> 6;
    const bool act = wv < 6;
    const int l = tid & 63, lm = l & 15, lq = l >> 4;
    const int g = wv % 3, mt = wv / 3;
    const int am = mt * 16 + lm;
    const int brow = g * 512 + dt * 16 + lm;
    float* pw = (float*)smem;                              // [8][16][17]
    unsigned short* h16 = (unsigned short*)(pw + 8 * 16 * 17);  // [512]
    p0a_worker(p, (bid - 32) * 512 + tid);
    while (sysld32(p.bar) != FLAGS_MAGIC) __builtin_amdgcn_s_sleep(1);
    p0bar(p.bar);
    // resident B-fragments
    bf8 WH[16], WD[8], WC[8];
    if (act) {
#pragma unroll
      for (int kt = 0; kt < 16; ++kt) WH[kt] = ldfrag(p.whhb + brow * 512 + kt * 32 + lq * 8);
#pragma unroll
      for (int kt = 0; kt < 8; ++kt) WD[kt] = ldfrag(p.wihb + brow * 512 + kt * 32 + lq * 8);
#pragma unroll
      for (int kt = 0; kt < 8; ++kt) WC[kt] = ldfrag(p.wihb + brow * 512 + 256 + kt * 32 + lq * 8);
    }
    for (int s = 0; s < 64; ++s) {
      // polls: all h(s) slices ready; mel far enough behind for h-ring reuse
      if (tid < 32) waitge(hdone + tid * 16, (unsigned)s);
      else if (tid < 34) waitge(meldone + (tid - 32) * 16, (s >= 4) ? (unsigned)(s - 3) : 0u);
      __syncthreads();
      // gh (needs h(s)) + gi_dec — overlaps att's softmax
      f32x4 acc = {0.f, 0.f, 0.f, 0.f};
      f32x4 gi = {0.f, 0.f, 0.f, 0.f};
      if (act) {
        const __hip_bfloat16* hb = p.hbf + (s & 3) * 16384;
#pragma unroll
        for (int kt = 0; kt < 16; ++kt) {
          bf8 a = ldfrag_sys(hb + am * 512 + kt * 32 + lq * 8);
          acc = MFMA16(a, WH[kt], acc);
        }
        const __hip_bfloat16* seqp = p.seqb + s * 8192;
#pragma unroll
        for (int kt = 0; kt < 8; ++kt) {
          bf8 a = ldfrag(seqp + am * 256 + kt * 32 + lq * 8);
          gi = MFMA16(a, WD[kt], gi);
        }
      }
      // wait ctx(s), then gi_ctx
      if (tid < 32) waitge(ctxdone + tid * 16, (unsigned)(s + 1));
      __syncthreads();
      if (act) {
        const __hip_bfloat16* ctxp = p.ctxb + (s & 3) * 8192;
#pragma unroll
        for (int kt = 0; kt < 8; ++kt) {
          bf8 a = ldfrag_sys(ctxp + am * 256 + kt * 32 + lq * 8);
          gi = MFMA16(a, WC[kt], gi);
        }
        if (g < 2) {
#pragma unroll
          for (int r = 0; r < 4; ++r) pw[(wv * 16 + lq * 4 + r) * 17 + lm] = acc[r] + gi[r];
        } else {
#pragma unroll
          for (int r = 0; r < 4; ++r) pw[(wv * 16 + lq * 4 + r) * 17 + lm] = acc[r];
#pragma unroll
          for (int r = 0; r < 4; ++r) pw[((6 + mt) * 16 + lq * 4 + r) * 17 + lm] = gi[r];
        }
      }
      __syncthreads();
      // pointwise: 512 threads = 32 b x 16 d
      {
        const int bb = tid >> 4, dl = tid & 15;
        const int mtb = bb >> 4, bl = bb & 15;
        float rg = sigm(pw[((mtb * 3 + 0) * 16 + bl) * 17 + dl]);
        float zg = sigm(pw[((mtb * 3 + 1) * 16 + bl) * 17 + dl]);
        float hn = pw[((mtb * 3 + 2) * 16 + bl) * 17 + dl];
        float inn = pw[((6 + mtb) * 16 + bl) * 17 + dl];
        float nn = tanhfast(fmaf(rg, hn, inn));
        const int d = dt * 16 + dl;
        const int idx = bb * 512 + d;
        unsigned w = sysld32((const unsigned*)(p.hbf + (s & 3) * 16384) + (idx >> 1));
        float ho = btof((idx & 1) ? (w >> 16) : (w & 0xffff));
        float hnew = fmaxf(0.0f, fmaf(zg, ho - nn, nn));  // relu((1-z)n+z*h)
        h16[bb * 16 + dl] = f2bfbits(hnew);
      }
      __syncthreads();
      if (tid < 256) {
        const int bb2 = tid >> 3, dp = tid & 7;
        unsigned v = (unsigned)h16[bb2 * 16 + dp * 2] |
                     ((unsigned)h16[bb2 * 16 + dp * 2 + 1] << 16);
        sysst32((unsigned*)(p.hbf + ((s + 1) & 3) * 16384) + bb2 * 256 + dt * 8 + dp, v);
      }
      __syncthreads();  // drains coherent stores
      if (tid == 0) sysst32(hdone + dt * 16, (unsigned)(s + 1));
    }
  } else {
    // ============================ MEL path ============================
    const int mt = bid - 64;  // batch half
    const int wv = tid >> 6;
    const bool act = wv < 6;
    const int l = tid & 63, lm = l & 15, lq = l >> 4;
    const int nt = wv;
    const int am = mt * 16 + lm, bn = nt * 16 + lm;
    p0a_worker(p, (bid - 32) * 512 + tid);
    while (sysld32(p.bar) != FLAGS_MAGIC) __builtin_amdgcn_s_sleep(1);
    p0bar(p.bar);
    bf8 WM[24];
    float bias = 0.f;
    if (act) {
#pragma unroll
      for (int kt = 0; kt < 24; ++kt) WM[kt] = ldfrag(p.wmelgb + bn * 768 + kt * 32 + lq * 8);
      bias = (bn < 80) ? p.bmel[bn] : ((bn == 80) ? p.bgate[0] : 0.f);
    }
    for (int tau = 0; tau < 64; ++tau) {
      if (tid < 32) waitge(hdone + tid * 16, (unsigned)(tau + 1));
      __syncthreads();
      if (act) {
        const __hip_bfloat16* ctxp = p.ctxb + (tau & 3) * 8192;
        const __hip_bfloat16* hb = p.hbf + ((tau + 1) & 3) * 16384;
        f32x4 acc = {0.f, 0.f, 0.f, 0.f};
#pragma unroll
        for (int kt = 0; kt < 24; ++kt) {
          bf8 a = (kt < 8) ? ldfrag_sys(ctxp + am * 256 + kt * 32 + lq * 8)
                           : ldfrag_sys(hb + am * 512 + (kt - 8) * 32 + lq * 8);
          acc = MFMA16(a, WM[kt], acc);
        }
#pragma unroll
        for (int r = 0; r < 4; ++r) {
          int bb = mt * 16 + lq * 4 + r;
          float v = acc[r] + bias;
          if (bn < 80)
            p.out[bb * 5120 + bn * 64 + tau] = v;
          else if (bn == 80)
            p.out[163840 + bb * 64 + tau] = v;
        }
      }
      __syncthreads();  // loads retired before signaling ring slots free
      if (tid == 0) sysst32(meldone + mt * 16, (unsigned)(tau + 1));
    }
  }
}

extern "C" void kernel_launch(void* const* d_in, const int* in_sizes, int n_in,
                              void* d_out, int out_size, void* d_ws, size_t ws_size,
                              hipStream_t stream) {
  Params P;
  P.dec = (const float*)d_in[0];
  P.ali = (const float*)d_in[1];
  P.watt = (const float*)d_in[2];
  P.wih = (const float*)d_in[3];
  P.whh = (const float*)d_in[4];
  P.wmel = (const float*)d_in[5];
  P.bmel = (const float*)d_in[6];
  P.wgate = (const float*)d_in[7];
  P.bgate = (const float*)d_in[8];
  P.out = (float*)d_out;

  char* w = (char*)d_ws;
  size_t o = 0;
  auto nxt = [&](size_t b) {
    char* r = w + o;
    o += (b + 255) & ~(size_t)255;
    return r;
  };
  P.bar = (unsigned*)nxt(8192);
  P.wihb = (__hip_bfloat16*)nxt(1536 * 512 * 2);
  P.whhb = (__hip_bfloat16*)nxt(1536 * 512 * 2);
  P.wmelgb = (__hip_bfloat16*)nxt(96 * 768 * 2);
  P.seqb = (__hip_bfloat16*)nxt(64 * 32 * 256 * 2);
  P.hbf = (__hip_bfloat16*)nxt(4 * 32 * 512 * 2);
  P.ctxb = (__hip_bfloat16*)nxt(4 * 32 * 256 * 2);
  P.wattp = (unsigned*)nxt(256 * 256 * 4);

  (void)hipFuncSetAttribute((const void*)rdec_kernel,
                            hipFuncAttributeMaxDynamicSharedMemorySize, SMEM_BYTES);

  void* args[] = {&P};
  hipError_t err = hipLaunchCooperativeKernel((void*)rdec_kernel, dim3(66), dim3(512),
                                              args, SMEM_BYTES, stream);
  if (err != hipSuccess) {
    // fallback: plain launch (66 blocks on 256 CUs -> trivially co-resident)
    rdec_kernel<<<dim3(66), dim3(512), SMEM_BYTES, stream>>>(P);
  }
}

// Round 7
// 1806.781 us; speedup vs baseline: 1.0620x; 1.0620x over previous
//
#include <hip/hip_runtime.h>
#include <hip/hip_bf16.h>

// ============================================================================
// RecurrentDecoder v7: 66-block persistent kernel, flag-based dataflow.
// v6 -> v7: cross-block data (h, ctx) is STAGED INTO LDS with batched
// system-scope loads (inline asm: 4x global_load_dwordx4 sc0 sc1 + ONE
// s_waitcnt). v6 serialized 32+ atomic loads per thread (vmcnt(0) each,
// ~0.4us apiece) inside GRU/mel MFMA loops -- that was the 30us/step.
//  - att blocks 0..31 (one per b): ali LDS-resident [e][t], W_att in VGPRs.
//  - GRU blocks 32..63 (16-col D-slice): weights VGPR-resident, h/ctx from LDS.
//  - mel blocks 64..65: staged h/ctx, off critical path (depth-4 rings).
// ============================================================================

#define LOG2E 1.4426950408889634f
#define FLAGS_MAGIC 0x13572468u
#define SMEM_BYTES 146432

typedef __attribute__((ext_vector_type(8))) short bf8;
typedef __attribute__((ext_vector_type(4))) float f32x4;
typedef __attribute__((ext_vector_type(4))) unsigned u32x4;
typedef unsigned long long ull;

#define EX2(x) exp2f(x)
#define MFMA16(a, b, c) __builtin_amdgcn_mfma_f32_16x16x32_bf16(a, b, c, 0, 0, 0)

struct Params {
  const float* dec;    // [64][32][256]
  const float* ali;    // [256][32][256]
  const float* watt;   // [256][512]
  const float* wih;    // [1536][512]
  const float* whh;    // [1536][512]
  const float* wmel;   // [80][768]
  const float* bmel;   // [80]
  const float* wgate;  // [768]
  const float* bgate;  // [1]
  float* out;          // mel 32*80*64 then gate 32*64
  unsigned* bar;       // [0]=magic [16]=p0cnt [32+16i]=hdone[i]
                       // [544+16i]=ctxdone[i] [1056+16m]=meldone[m]
  __hip_bfloat16* wihb;    // [1536][512]
  __hip_bfloat16* whhb;    // [1536][512]
  __hip_bfloat16* wmelgb;  // [96][768]
  __hip_bfloat16* seqb;    // [64][32][256]
  __hip_bfloat16* hbf;     // ring [4][32][512]
  __hip_bfloat16* ctxb;    // ring [4][32][256]
  unsigned* wattp;         // [256][256] packed bf16 pairs of W_att^T
};

__device__ __forceinline__ bf8 ldfrag(const __hip_bfloat16* p) {
  return *(const bf8*)p;
}
__device__ __forceinline__ float sigm(float x) {
  return 1.0f / (1.0f + EX2(-x * LOG2E));
}
__device__ __forceinline__ float tanhfast(float x) {
  x = fminf(fmaxf(x, -15.0f), 15.0f);
  float e = EX2(x * (2.0f * LOG2E));
  return (e - 1.0f) / (e + 1.0f);
}
__device__ __forceinline__ float btof(unsigned v) {
  return __uint_as_float(v << 16);
}
__device__ __forceinline__ unsigned short f2bfbits(float x) {
  __hip_bfloat16 h = __float2bfloat16(x);
  return *(unsigned short*)&h;
}
// --- system-scope (sc0 sc1) coherent accessors ---
__device__ __forceinline__ unsigned sysld32(const unsigned* p) {
  return __hip_atomic_load(p, __ATOMIC_RELAXED, __HIP_MEMORY_SCOPE_SYSTEM);
}
__device__ __forceinline__ ull sysld64(const ull* p) {
  return __hip_atomic_load(p, __ATOMIC_RELAXED, __HIP_MEMORY_SCOPE_SYSTEM);
}
__device__ __forceinline__ void sysst32(unsigned* p, unsigned v) {
  __hip_atomic_store(p, v, __ATOMIC_RELAXED, __HIP_MEMORY_SCOPE_SYSTEM);
}
__device__ __forceinline__ void sysst64(ull* p, ull v) {
  __hip_atomic_store(p, v, __ATOMIC_RELAXED, __HIP_MEMORY_SCOPE_SYSTEM);
}
// Batched coherent 16B loads: N independent loads, ONE waitcnt.
__device__ __forceinline__ void sysld16x4(u32x4* d0, u32x4* d1, u32x4* d2, u32x4* d3,
                                          const void* p0, const void* p1,
                                          const void* p2, const void* p3) {
  u32x4 a, b, c, d;
  asm volatile(
      "global_load_dwordx4 %0, %4, off sc0 sc1\n\t"
      "global_load_dwordx4 %1, %5, off sc0 sc1\n\t"
      "global_load_dwordx4 %2, %6, off sc0 sc1\n\t"
      "global_load_dwordx4 %3, %7, off sc0 sc1\n\t"
      "s_waitcnt vmcnt(0)"
      : "=&v"(a), "=&v"(b), "=&v"(c), "=&v"(d)
      : "v"(p0), "v"(p1), "v"(p2), "v"(p3)
      : "memory");
  *d0 = a; *d1 = b; *d2 = c; *d3 = d;
}
__device__ __forceinline__ void sysld16x2(u32x4* d0, u32x4* d1,
                                          const void* p0, const void* p1) {
  u32x4 a, b;
  asm volatile(
      "global_load_dwordx4 %0, %2, off sc0 sc1\n\t"
      "global_load_dwordx4 %1, %3, off sc0 sc1\n\t"
      "s_waitcnt vmcnt(0)"
      : "=&v"(a), "=&v"(b)
      : "v"(p0), "v"(p1)
      : "memory");
  *d0 = a; *d1 = b;
}
__device__ __forceinline__ void waitge(unsigned* w, unsigned tgt) {
  while (sysld32(w) < tgt) __builtin_amdgcn_s_sleep(1);
}

// One-time P0 barrier (66 blocks) with agent fences for the plain-store
// converted-weight handoff (pattern proven in v4-v6).
__device__ __forceinline__ void p0bar(unsigned* bar) {
  __syncthreads();
  if (threadIdx.x == 0) {
    __builtin_amdgcn_fence(__ATOMIC_RELEASE, "agent");
    __hip_atomic_fetch_add(bar + 16, 1u, __ATOMIC_RELAXED, __HIP_MEMORY_SCOPE_SYSTEM);
    while (sysld32(bar + 16) < 66u) __builtin_amdgcn_s_sleep(1);
    __builtin_amdgcn_fence(__ATOMIC_ACQUIRE, "agent");
  }
  __syncthreads();
}

// P0 conversion work for blocks 32..65 (wid in [0, 34*512))
__device__ __forceinline__ void p0a_worker(const Params& p, int wid) {
  for (int i = wid; i < 2252800; i += 17408) {
    if (i < 786432) {
      p.wihb[i] = __float2bfloat16(p.wih[i]);
    } else if (i < 1572864) {
      int j = i - 786432;
      p.whhb[j] = __float2bfloat16(p.whh[j]);
    } else if (i < 2097152) {
      int j = i - 1572864;
      int s = j >> 13;
      p.seqb[j] = (s == 0) ? __float2bfloat16(0.0f) : __float2bfloat16(p.dec[j - 8192]);
    } else if (i < 2170880) {
      int j = i - 2097152;
      int r = j / 768, c = j - r * 768;
      float v = (r < 80) ? p.wmel[j] : ((r == 80) ? p.wgate[c] : 0.0f);
      p.wmelgb[j] = __float2bfloat16(v);
    } else if (i < 2236416) {
      int j = i - 2170880;
      int kp = j >> 8, e = j & 255;
      unsigned lo = f2bfbits(p.watt[e * 512 + 2 * kp]);
      unsigned hi = f2bfbits(p.watt[e * 512 + 2 * kp + 1]);
      p.wattp[j] = lo | (hi << 16);
    } else {
      int j = i - 2236416;
      p.hbf[j] = __float2bfloat16(0.0f);  // h ring slot 0 = h(0) = 0
    }
  }
}

__global__ void __launch_bounds__(512, 1) rdec_kernel(Params p) {
  const int tid = threadIdx.x;
  const int bid = blockIdx.x;
  extern __shared__ char smem[];
  unsigned* hdone = p.bar + 32;      // stride 16
  unsigned* ctxdone = p.bar + 544;   // stride 16
  unsigned* meldone = p.bar + 1056;  // stride 16

  // ---- flag init (ws poisoned 0xAA each launch) ----
  if (bid == 0) {
    for (int i = 1 + tid; i < 1100; i += 512) sysst32(p.bar + i, 0u);
    __syncthreads();
    if (tid == 0) sysst32(p.bar, FLAGS_MAGIC);
  }

  if (bid < 32) {
    // ============================ ATT path ============================
    const int b = bid;
    unsigned short* alds = (unsigned short*)smem;  // [256][260] bf16, [e][t]
    float* shh = (float*)(smem + 256 * 260 * 2);   // 512
    float* shp = shh + 512;                        // 256
    float* shr = shp + 256;                        // 256
    float* shtw = shr + 256;                       // 256
    float* pA = shtw + 256;                        // 512
    float* pB = pA + 512;
    float* pC = pB + 512;
    float* pD = pC + 512;
    unsigned short* pc16 = (unsigned short*)pC;
    const int e = tid & 255, th = tid >> 8;

    // P0: ali -> LDS bf16 in [e][t] layout
    for (int i = tid; i < 65536; i += 512) {
      int t = i >> 8, ee = i & 255;
      alds[ee * 260 + t] = f2bfbits(p.ali[t * 8192 + b * 256 + ee]);
    }
    if (tid == 0) {
      while (sysld32(p.bar) != FLAGS_MAGIC) __builtin_amdgcn_s_sleep(1);
    }
    p0bar(p.bar);
    // resident W_att^T slice
    unsigned wr[128];
#pragma unroll
    for (int i = 0; i < 128; ++i) wr[i] = p.wattp[(th * 128 + i) * 256 + e];

    for (int s = 0; s < 64; ++s) {
      if (tid < 32) waitge(hdone + tid * 16, (unsigned)s);
      else if (tid < 34) waitge(meldone + (tid - 32) * 16, (s >= 4) ? (unsigned)(s - 3) : 0u);
      __syncthreads();
      // load h(s)[b,:] (one batched coherent round)
      if (tid < 128) {
        ull w = sysld64((const ull*)(p.hbf + (s & 3) * 16384 + b * 512) + tid);
        shh[tid * 4 + 0] = btof((unsigned)(w & 0xffff));
        shh[tid * 4 + 1] = btof((unsigned)((w >> 16) & 0xffff));
        shh[tid * 4 + 2] = btof((unsigned)((w >> 32) & 0xffff));
        shh[tid * 4 + 3] = btof((unsigned)((w >> 48) & 0xffff));
      }
      __syncthreads();
      // proj partial (k-split by th) from resident registers
      {
        float acc = 0.f;
        const float2* h2 = (const float2*)shh;
#pragma unroll
        for (int i = 0; i < 128; ++i) {
          unsigned w = wr[i];
          float2 hv = h2[th * 128 + i];
          acc = fmaf(__uint_as_float(w << 16), hv.x, acc);
          acc = fmaf(__uint_as_float(w & 0xffff0000u), hv.y, acc);
        }
        pA[th * 256 + e] = acc;
      }
      __syncthreads();
      const float p2 = (pA[e] + pA[256 + e]) * LOG2E;
      if (tid < 256) shp[e] = p2;
      // denominator partial (t-split by th)
      {
        const ushort4* row = (const ushort4*)(alds + e * 260 + th * 128);
        float d0 = 0.f;
#pragma unroll 8
        for (int q = 0; q < 32; ++q) {
          ushort4 v = row[q];
          d0 += EX2(btof(v.x) * p2);
          d0 += EX2(btof(v.y) * p2);
          d0 += EX2(btof(v.z) * p2);
          d0 += EX2(btof(v.w) * p2);
        }
        pB[th * 256 + e] = d0;
      }
      __syncthreads();
      if (tid < 256) shr[e] = 1.0f / (pB[e] + pB[256 + e]);
      __syncthreads();
      // tw partial (e-split by th)
      {
        const int t = tid & 255;
        float acc = 0.f;
        const int e0 = th * 128;
#pragma unroll 8
        for (int ee = e0; ee < e0 + 128; ++ee) {
          acc += EX2(btof(alds[ee * 260 + t]) * shp[ee]) * shr[ee];
        }
        pC[th * 256 + t] = acc;
      }
      __syncthreads();
      if (tid < 256) shtw[tid] = pC[tid] + pC[256 + tid];
      __syncthreads();
      // ctx partial (t-split by th)
      {
        const ushort4* row = (const ushort4*)(alds + e * 260 + th * 128);
        const float* twp = shtw + th * 128;
        float c0 = 0.f;
#pragma unroll 8
        for (int q = 0; q < 32; ++q) {
          ushort4 v = row[q];
          c0 += twp[q * 4 + 0] * btof(v.x);
          c0 += twp[q * 4 + 1] * btof(v.y);
          c0 += twp[q * 4 + 2] * btof(v.z);
          c0 += twp[q * 4 + 3] * btof(v.w);
        }
        pD[th * 256 + e] = c0;
      }
      __syncthreads();
      if (tid < 256) pc16[e] = f2bfbits(pD[e] + pD[256 + e]);
      __syncthreads();
      if (tid < 64)
        sysst64((ull*)(p.ctxb + (s & 3) * 8192 + b * 256) + tid, ((const ull*)pc16)[tid]);
      __syncthreads();  // drains stores (vmcnt) before flag
      if (tid == 0) sysst32(ctxdone + b * 16, (unsigned)(s + 1));
    }
  } else if (bid < 64) {
    // ============================ GRU path ============================
    const int dt = bid - 32;
    const int wv = tid >> 6;
    const bool act = wv < 6;
    const int l = tid & 63, lm = l & 15, lq = l >> 4;
    const int g = wv % 3, mt = wv / 3;
    const int am = mt * 16 + lm;
    const int brow = g * 512 + dt * 16 + lm;
    __hip_bfloat16* hA = (__hip_bfloat16*)smem;             // [32][512] 32 KB
    __hip_bfloat16* cA = (__hip_bfloat16*)(smem + 32768);   // [32][256] 16 KB
    float* pw = (float*)(smem + 49152);                     // [8][16][17]
    unsigned short* h16 = (unsigned short*)(smem + 57856);  // [512]
    unsigned short* hAu = (unsigned short*)hA;
    p0a_worker(p, (bid - 32) * 512 + tid);
    if (tid == 0) {
      while (sysld32(p.bar) != FLAGS_MAGIC) __builtin_amdgcn_s_sleep(1);
    }
    p0bar(p.bar);
    // resident B-fragments
    bf8 WH[16], WD[8], WC[8];
    if (act) {
#pragma unroll
      for (int kt = 0; kt < 16; ++kt) WH[kt] = ldfrag(p.whhb + brow * 512 + kt * 32 + lq * 8);
#pragma unroll
      for (int kt = 0; kt < 8; ++kt) WD[kt] = ldfrag(p.wihb + brow * 512 + kt * 32 + lq * 8);
#pragma unroll
      for (int kt = 0; kt < 8; ++kt) WC[kt] = ldfrag(p.wihb + brow * 512 + 256 + kt * 32 + lq * 8);
    }
    for (int s = 0; s < 64; ++s) {
      if (tid < 32) waitge(hdone + tid * 16, (unsigned)s);
      else if (tid < 34) waitge(meldone + (tid - 32) * 16, (s >= 4) ? (unsigned)(s - 3) : 0u);
      __syncthreads();
      // stage h(s) -> LDS: 32KB, 4 chunks/thread, ONE waitcnt
      {
        const char* hsrc = (const char*)(p.hbf + (s & 3) * 16384);
        u32x4 a, b, c, d;
        sysld16x4(&a, &b, &c, &d, hsrc + tid * 16, hsrc + (tid + 512) * 16,
                  hsrc + (tid + 1024) * 16, hsrc + (tid + 1536) * 16);
        u32x4* hd = (u32x4*)hA;
        hd[tid] = a; hd[tid + 512] = b; hd[tid + 1024] = c; hd[tid + 1536] = d;
      }
      __syncthreads();
      // gh from LDS + gi_dec from cached seqb (overlaps att's softmax)
      f32x4 acc = {0.f, 0.f, 0.f, 0.f};
      f32x4 gi = {0.f, 0.f, 0.f, 0.f};
      if (act) {
#pragma unroll
        for (int kt = 0; kt < 16; ++kt) {
          bf8 a = ldfrag(hA + am * 512 + kt * 32 + lq * 8);
          acc = MFMA16(a, WH[kt], acc);
        }
        const __hip_bfloat16* seqp = p.seqb + s * 8192;
#pragma unroll
        for (int kt = 0; kt < 8; ++kt) {
          bf8 a = ldfrag(seqp + am * 256 + kt * 32 + lq * 8);
          gi = MFMA16(a, WD[kt], gi);
        }
      }
      // wait ctx(s), stage to LDS, gi_ctx
      if (tid < 32) waitge(ctxdone + tid * 16, (unsigned)(s + 1));
      __syncthreads();
      {
        const char* csrc = (const char*)(p.ctxb + (s & 3) * 8192);
        u32x4 a, b;
        sysld16x2(&a, &b, csrc + tid * 16, csrc + (tid + 512) * 16);
        u32x4* cd = (u32x4*)cA;
        cd[tid] = a; cd[tid + 512] = b;
      }
      __syncthreads();
      if (act) {
#pragma unroll
        for (int kt = 0; kt < 8; ++kt) {
          bf8 a = ldfrag(cA + am * 256 + kt * 32 + lq * 8);
          gi = MFMA16(a, WC[kt], gi);
        }
        if (g < 2) {
#pragma unroll
          for (int r = 0; r < 4; ++r) pw[(wv * 16 + lq * 4 + r) * 17 + lm] = acc[r] + gi[r];
        } else {
#pragma unroll
          for (int r = 0; r < 4; ++r) pw[(wv * 16 + lq * 4 + r) * 17 + lm] = acc[r];
#pragma unroll
          for (int r = 0; r < 4; ++r) pw[((6 + mt) * 16 + lq * 4 + r) * 17 + lm] = gi[r];
        }
      }
      __syncthreads();
      // pointwise: 512 threads = 32 b x 16 d; old h read from LDS
      {
        const int bb = tid >> 4, dl = tid & 15;
        const int mtb = bb >> 4, bl = bb & 15;
        float rg = sigm(pw[((mtb * 3 + 0) * 16 + bl) * 17 + dl]);
        float zg = sigm(pw[((mtb * 3 + 1) * 16 + bl) * 17 + dl]);
        float hn = pw[((mtb * 3 + 2) * 16 + bl) * 17 + dl];
        float inn = pw[((6 + mtb) * 16 + bl) * 17 + dl];
        float nn = tanhfast(fmaf(rg, hn, inn));
        const int d = dt * 16 + dl;
        float ho = btof(hAu[bb * 512 + d]);
        float hnew = fmaxf(0.0f, fmaf(zg, ho - nn, nn));  // relu((1-z)n+z*h)
        h16[bb * 16 + dl] = f2bfbits(hnew);
      }
      __syncthreads();
      if (tid < 256) {
        const int bb2 = tid >> 3, dp = tid & 7;
        unsigned v = (unsigned)h16[bb2 * 16 + dp * 2] |
                     ((unsigned)h16[bb2 * 16 + dp * 2 + 1] << 16);
        sysst32((unsigned*)(p.hbf + ((s + 1) & 3) * 16384) + bb2 * 256 + dt * 8 + dp, v);
      }
      __syncthreads();  // drains stores before flag
      if (tid == 0) sysst32(hdone + dt * 16, (unsigned)(s + 1));
    }
  } else {
    // ============================ MEL path ============================
    const int mt = bid - 64;  // batch half
    const int wv = tid >> 6;
    const bool act = wv < 6;
    const int l = tid & 63, lm = l & 15, lq = l >> 4;
    const int nt = wv;
    const int am = mt * 16 + lm, bn = nt * 16 + lm;
    __hip_bfloat16* hA = (__hip_bfloat16*)smem;            // [32][512]
    __hip_bfloat16* cA = (__hip_bfloat16*)(smem + 32768);  // [32][256]
    p0a_worker(p, (bid - 32) * 512 + tid);
    if (tid == 0) {
      while (sysld32(p.bar) != FLAGS_MAGIC) __builtin_amdgcn_s_sleep(1);
    }
    p0bar(p.bar);
    bf8 WM[24];
    float bias = 0.f;
    if (act) {
#pragma unroll
      for (int kt = 0; kt < 24; ++kt) WM[kt] = ldfrag(p.wmelgb + bn * 768 + kt * 32 + lq * 8);
      bias = (bn < 80) ? p.bmel[bn] : ((bn == 80) ? p.bgate[0] : 0.f);
    }
    for (int tau = 0; tau < 64; ++tau) {
      if (tid < 32) waitge(hdone + tid * 16, (unsigned)(tau + 1));
      __syncthreads();
      // stage h(tau+1) + ctx(tau)
      {
        const char* hsrc = (const char*)(p.hbf + ((tau + 1) & 3) * 16384);
        u32x4 a, b, c, d;
        sysld16x4(&a, &b, &c, &d, hsrc + tid * 16, hsrc + (tid + 512) * 16,
                  hsrc + (tid + 1024) * 16, hsrc + (tid + 1536) * 16);
        u32x4* hd = (u32x4*)hA;
        hd[tid] = a; hd[tid + 512] = b; hd[tid + 1024] = c; hd[tid + 1536] = d;
        const char* csrc = (const char*)(p.ctxb + (tau & 3) * 8192);
        u32x4 e0, e1;
        sysld16x2(&e0, &e1, csrc + tid * 16, csrc + (tid + 512) * 16);
        u32x4* cd = (u32x4*)cA;
        cd[tid] = e0; cd[tid + 512] = e1;
      }
      __syncthreads();
      if (act) {
        f32x4 acc = {0.f, 0.f, 0.f, 0.f};
#pragma unroll
        for (int kt = 0; kt < 24; ++kt) {
          bf8 a = (kt < 8) ? ldfrag(cA + am * 256 + kt * 32 + lq * 8)
                           : ldfrag(hA + am * 512 + (kt - 8) * 32 + lq * 8);
          acc = MFMA16(a, WM[kt], acc);
        }
#pragma unroll
        for (int r = 0; r < 4; ++r) {
          int bb = mt * 16 + lq * 4 + r;
          float v = acc[r] + bias;
          if (bn < 80)
            p.out[bb * 5120 + bn * 64 + tau] = v;
          else if (bn == 80)
            p.out[163840 + bb * 64 + tau] = v;
        }
      }
      __syncthreads();
      if (tid == 0) sysst32(meldone + mt * 16, (unsigned)(tau + 1));
    }
  }
}

extern "C" void kernel_launch(void* const* d_in, const int* in_sizes, int n_in,
                              void* d_out, int out_size, void* d_ws, size_t ws_size,
                              hipStream_t stream) {
  Params P;
  P.dec = (const float*)d_in[0];
  P.ali = (const float*)d_in[1];
  P.watt = (const float*)d_in[2];
  P.wih = (const float*)d_in[3];
  P.whh = (const float*)d_in[4];
  P.wmel = (const float*)d_in[5];
  P.bmel = (const float*)d_in[6];
  P.wgate = (const float*)d_in[7];
  P.bgate = (const float*)d_in[8];
  P.out = (float*)d_out;

  char* w = (char*)d_ws;
  size_t o = 0;
  auto nxt = [&](size_t b) {
    char* r = w + o;
    o += (b + 255) & ~(size_t)255;
    return r;
  };
  P.bar = (unsigned*)nxt(8192);
  P.wihb = (__hip_bfloat16*)nxt(1536 * 512 * 2);
  P.whhb = (__hip_bfloat16*)nxt(1536 * 512 * 2);
  P.wmelgb = (__hip_bfloat16*)nxt(96 * 768 * 2);
  P.seqb = (__hip_bfloat16*)nxt(64 * 32 * 256 * 2);
  P.hbf = (__hip_bfloat16*)nxt(4 * 32 * 512 * 2);
  P.ctxb = (__hip_bfloat16*)nxt(4 * 32 * 256 * 2);
  P.wattp = (unsigned*)nxt(256 * 256 * 4);

  (void)hipFuncSetAttribute((const void*)rdec_kernel,
                            hipFuncAttributeMaxDynamicSharedMemorySize, SMEM_BYTES);

  void* args[] = {&P};
  hipError_t err = hipLaunchCooperativeKernel((void*)rdec_kernel, dim3(66), dim3(512),
                                              args, SMEM_BYTES, stream);
  if (err != hipSuccess) {
    // fallback: plain launch (66 blocks on 256 CUs -> trivially co-resident)
    rdec_kernel<<<dim3(66), dim3(512), SMEM_BYTES, stream>>>(P);
  }
}

// Round 9
// 1607.186 us; speedup vs baseline: 1.1939x; 1.1242x over previous
//
#include <hip/hip_runtime.h>
#include <hip/hip_bf16.h>

// ============================================================================
// RecurrentDecoder v9: v8 with the att-path LDS overflow fixed.
// v8 bug: att scratch (pD/pc16) extended 2048B past the 148480B dynamic-LDS
// allocation -> OOB LDS (reads 0 / writes dropped) -> ctx==0 -> absmax 20.
// v9: pD aliases pA (dead after shpr is built); total == SMEM_BYTES exactly.
// Also de-diverged the pc16-aliasing barrier.
// Everything else identical to v8 (swizzled alds, b64 tw pass, fragment-major
// h/ctx staging, v7 flag dataflow).
// ============================================================================

#define LOG2E 1.4426950408889634f
#define FLAGS_MAGIC 0x13572468u
#define SMEM_BYTES 148480

typedef __attribute__((ext_vector_type(8))) short bf8;
typedef __attribute__((ext_vector_type(4))) float f32x4;
typedef __attribute__((ext_vector_type(4))) unsigned u32x4;
typedef unsigned long long ull;

#define EX2(x) exp2f(x)
#define MFMA16(a, b, c) __builtin_amdgcn_mfma_f32_16x16x32_bf16(a, b, c, 0, 0, 0)

struct Params {
  const float* dec;
  const float* ali;
  const float* watt;
  const float* wih;
  const float* whh;
  const float* wmel;
  const float* bmel;
  const float* wgate;
  const float* bgate;
  float* out;
  unsigned* bar;  // [0]=magic [16]=p0cnt [32+16i]=hdone [544+16i]=ctxdone [1056+16m]=meldone
  __hip_bfloat16* wihb;    // [1536][512]
  __hip_bfloat16* whhb;    // [1536][512]
  __hip_bfloat16* wmelgb;  // [96][768]
  __hip_bfloat16* seqb;    // [64][32][256]
  __hip_bfloat16* hbf;     // ring [4][32][512]
  __hip_bfloat16* ctxb;    // ring [4][32][256]
  unsigned* wattp;         // [256][256] packed bf16 pairs of W_att^T
};

__device__ __forceinline__ bf8 ldfrag(const __hip_bfloat16* p) { return *(const bf8*)p; }
__device__ __forceinline__ float sigm(float x) { return 1.0f / (1.0f + EX2(-x * LOG2E)); }
__device__ __forceinline__ float tanhfast(float x) {
  x = fminf(fmaxf(x, -15.0f), 15.0f);
  float e = EX2(x * (2.0f * LOG2E));
  return (e - 1.0f) / (e + 1.0f);
}
__device__ __forceinline__ float btof(unsigned v) { return __uint_as_float(v << 16); }
__device__ __forceinline__ unsigned short f2bfbits(float x) {
  __hip_bfloat16 h = __float2bfloat16(x);
  return *(unsigned short*)&h;
}
__device__ __forceinline__ unsigned sysld32(const unsigned* p) {
  return __hip_atomic_load(p, __ATOMIC_RELAXED, __HIP_MEMORY_SCOPE_SYSTEM);
}
__device__ __forceinline__ ull sysld64(const ull* p) {
  return __hip_atomic_load(p, __ATOMIC_RELAXED, __HIP_MEMORY_SCOPE_SYSTEM);
}
__device__ __forceinline__ void sysst32(unsigned* p, unsigned v) {
  __hip_atomic_store(p, v, __ATOMIC_RELAXED, __HIP_MEMORY_SCOPE_SYSTEM);
}
__device__ __forceinline__ void sysst64(ull* p, ull v) {
  __hip_atomic_store(p, v, __ATOMIC_RELAXED, __HIP_MEMORY_SCOPE_SYSTEM);
}
// Batched coherent 16B loads: independent loads, ONE waitcnt.
__device__ __forceinline__ void sysld16x4(u32x4* d0, u32x4* d1, u32x4* d2, u32x4* d3,
                                          const void* p0, const void* p1,
                                          const void* p2, const void* p3) {
  u32x4 a, b, c, d;
  asm volatile(
      "global_load_dwordx4 %0, %4, off sc0 sc1\n\t"
      "global_load_dwordx4 %1, %5, off sc0 sc1\n\t"
      "global_load_dwordx4 %2, %6, off sc0 sc1\n\t"
      "global_load_dwordx4 %3, %7, off sc0 sc1\n\t"
      "s_waitcnt vmcnt(0)"
      : "=&v"(a), "=&v"(b), "=&v"(c), "=&v"(d)
      : "v"(p0), "v"(p1), "v"(p2), "v"(p3)
      : "memory");
  *d0 = a; *d1 = b; *d2 = c; *d3 = d;
}
__device__ __forceinline__ void sysld16x2(u32x4* d0, u32x4* d1,
                                          const void* p0, const void* p1) {
  u32x4 a, b;
  asm volatile(
      "global_load_dwordx4 %0, %2, off sc0 sc1\n\t"
      "global_load_dwordx4 %1, %3, off sc0 sc1\n\t"
      "s_waitcnt vmcnt(0)"
      : "=&v"(a), "=&v"(b)
      : "v"(p0), "v"(p1)
      : "memory");
  *d0 = a; *d1 = b;
}
__device__ __forceinline__ void waitge(unsigned* w, unsigned tgt) {
  while (sysld32(w) < tgt) __builtin_amdgcn_s_sleep(1);
}

__device__ __forceinline__ void p0bar(unsigned* bar) {
  __syncthreads();
  if (threadIdx.x == 0) {
    __builtin_amdgcn_fence(__ATOMIC_RELEASE, "agent");
    __hip_atomic_fetch_add(bar + 16, 1u, __ATOMIC_RELAXED, __HIP_MEMORY_SCOPE_SYSTEM);
    while (sysld32(bar + 16) < 66u) __builtin_amdgcn_s_sleep(1);
    __builtin_amdgcn_fence(__ATOMIC_ACQUIRE, "agent");
  }
  __syncthreads();
}

__device__ __forceinline__ void p0a_worker(const Params& p, int wid) {
  for (int i = wid; i < 2252800; i += 17408) {
    if (i < 786432) {
      p.wihb[i] = __float2bfloat16(p.wih[i]);
    } else if (i < 1572864) {
      int j = i - 786432;
      p.whhb[j] = __float2bfloat16(p.whh[j]);
    } else if (i < 2097152) {
      int j = i - 1572864;
      int s = j >> 13;
      p.seqb[j] = (s == 0) ? __float2bfloat16(0.0f) : __float2bfloat16(p.dec[j - 8192]);
    } else if (i < 2170880) {
      int j = i - 2097152;
      int r = j / 768, c = j - r * 768;
      float v = (r < 80) ? p.wmel[j] : ((r == 80) ? p.wgate[c] : 0.0f);
      p.wmelgb[j] = __float2bfloat16(v);
    } else if (i < 2236416) {
      int j = i - 2170880;
      int kp = j >> 8, e = j & 255;
      unsigned lo = f2bfbits(p.watt[e * 512 + 2 * kp]);
      unsigned hi = f2bfbits(p.watt[e * 512 + 2 * kp + 1]);
      p.wattp[j] = lo | (hi << 16);
    } else {
      int j = i - 2236416;
      p.hbf[j] = __float2bfloat16(0.0f);
    }
  }
}

// Stage h[32][512] bf16 (row-major global) into fragment-major LDS:
// section idx=(mt*16+kt) in [0,32), chunk (lq*16+lm) -> lane-contiguous 16B.
__device__ __forceinline__ void stage_h_frag(__hip_bfloat16* hA,
                                             const __hip_bfloat16* hsrc, int tid) {
  const int lm = tid & 15, lq = (tid >> 4) & 3, wq = tid >> 6;
  const int dst_in = (lq * 16 + lm) * 8;
  const int i0 = 0 * 8 + wq, i1 = 1 * 8 + wq, i2 = 2 * 8 + wq, i3 = 3 * 8 + wq;
  auto soff = [&](int idx) {
    return ((idx >> 4) * 16 + lm) * 512 + (idx & 15) * 32 + lq * 8;
  };
  u32x4 a, b, c, d;
  sysld16x4(&a, &b, &c, &d, hsrc + soff(i0), hsrc + soff(i1), hsrc + soff(i2),
            hsrc + soff(i3));
  u32x4* dst = (u32x4*)hA;
  dst[(i0 * 512 + dst_in) >> 3] = a;
  dst[(i1 * 512 + dst_in) >> 3] = b;
  dst[(i2 * 512 + dst_in) >> 3] = c;
  dst[(i3 * 512 + dst_in) >> 3] = d;
}
// Stage ctx[32][256] into fragment-major: section idx=(mt*8+kt) in [0,16).
__device__ __forceinline__ void stage_c_frag(__hip_bfloat16* cA,
                                             const __hip_bfloat16* csrc, int tid) {
  const int lm = tid & 15, lq = (tid >> 4) & 3, wq = tid >> 6;
  const int dst_in = (lq * 16 + lm) * 8;
  const int i0 = wq, i1 = 8 + wq;
  auto soff = [&](int idx) {
    return ((idx >> 3) * 16 + lm) * 256 + (idx & 7) * 32 + lq * 8;
  };
  u32x4 a, b;
  sysld16x2(&a, &b, csrc + soff(i0), csrc + soff(i1));
  u32x4* dst = (u32x4*)cA;
  dst[(i0 * 512 + dst_in) >> 3] = a;
  dst[(i1 * 512 + dst_in) >> 3] = b;
}

__global__ void __launch_bounds__(512, 1) rdec_kernel(Params p) {
  const int tid = threadIdx.x;
  const int bid = blockIdx.x;
  extern __shared__ char smem[];
  unsigned* hdone = p.bar + 32;
  unsigned* ctxdone = p.bar + 544;
  unsigned* meldone = p.bar + 1056;

  if (bid == 0) {
    for (int i = 1 + tid; i < 1100; i += 512) sysst32(p.bar + i, 0u);
    __syncthreads();
    if (tid == 0) sysst32(p.bar, FLAGS_MAGIC);
  }

  if (bid < 32) {
    // ============================ ATT path ============================
    const int b = bid;
    unsigned short* alds = (unsigned short*)smem;  // [256][256] swizzled, 128KB
    float* shh = (float*)(smem + 131072);          // 512
    float* shpr = shh + 512;                       // 512 (float2 per e)
    float* shtw = shpr + 512;                      // 256
    float* pA = shtw + 256;                        // 512
    float* pB = pA + 512;                          // 512
    float* pC = pB + 512;                          // 2048 ([8][256])
    float* pD = pA;                                // ALIAS: pA dead after shpr
    unsigned short* pc16 = (unsigned short*)pA;    // alias of pD
    const int e = tid & 255, th = tid >> 8;
    // total after alds: (512+512+256+512+512+2048)*4 = 17408B -> 148480 exact.

    // P0: ali -> swizzled LDS. elem (e,t) at u16 addr e*256+((t>>2)^(e&31))*4+(t&3)
    for (int i = tid; i < 65536; i += 512) {
      int t = i >> 8, ee = i & 255;
      alds[ee * 256 + (((t >> 2) ^ (ee & 31)) << 2) + (t & 3)] =
          f2bfbits(p.ali[t * 8192 + b * 256 + ee]);
    }
    if (tid == 0) {
      while (sysld32(p.bar) != FLAGS_MAGIC) __builtin_amdgcn_s_sleep(1);
    }
    p0bar(p.bar);
    unsigned wr[128];
#pragma unroll
    for (int i = 0; i < 128; ++i) wr[i] = p.wattp[(th * 128 + i) * 256 + e];

    for (int s = 0; s < 64; ++s) {
      if (tid < 32) waitge(hdone + tid * 16, (unsigned)s);
      else if (tid < 34) waitge(meldone + (tid - 32) * 16, (s >= 4) ? (unsigned)(s - 3) : 0u);
      __syncthreads();
      if (tid < 128) {
        ull w = sysld64((const ull*)(p.hbf + (s & 3) * 16384 + b * 512) + tid);
        shh[tid * 4 + 0] = btof((unsigned)(w & 0xffff));
        shh[tid * 4 + 1] = btof((unsigned)((w >> 16) & 0xffff));
        shh[tid * 4 + 2] = btof((unsigned)((w >> 32) & 0xffff));
        shh[tid * 4 + 3] = btof((unsigned)((w >> 48) & 0xffff));
      }
      __syncthreads();
      // proj partial (k-split by th)
      {
        float acc = 0.f;
        const float2* h2 = (const float2*)shh;
#pragma unroll
        for (int i = 0; i < 128; ++i) {
          unsigned w = wr[i];
          float2 hv = h2[th * 128 + i];
          acc = fmaf(__uint_as_float(w << 16), hv.x, acc);
          acc = fmaf(__uint_as_float(w & 0xffff0000u), hv.y, acc);
        }
        pA[th * 256 + e] = acc;
      }
      __syncthreads();
      // denominator partial (t-granules th*32..th*32+31)
      {
        const float p2 = (pA[e] + pA[256 + e]) * LOG2E;
        const int sw = e & 31;
        float d0 = 0.f, d1 = 0.f;
#pragma unroll 8
        for (int q = 0; q < 32; ++q) {
          int g = th * 32 + q;
          ushort4 v = *(const ushort4*)(alds + e * 256 + ((g ^ sw) << 2));
          d0 += EX2(btof(v.x) * p2) + EX2(btof(v.y) * p2);
          d1 += EX2(btof(v.z) * p2) + EX2(btof(v.w) * p2);
        }
        pB[th * 256 + e] = d0 + d1;
      }
      __syncthreads();
      if (tid < 256) {
        float p2 = (pA[e] + pA[256 + e]) * LOG2E;
        ((float2*)shpr)[e] = make_float2(p2, 1.0f / (pB[e] + pB[256 + e]));
      }
      __syncthreads();
      // tw: thread owns t-quad tq (granule tq), iterates 32 e's
      {
        const int es = tid >> 6, tq = tid & 63;
        float a0 = 0.f, a1 = 0.f, a2 = 0.f, a3 = 0.f;
#pragma unroll 8
        for (int j = 0; j < 32; ++j) {
          int ee = es * 32 + j;
          float2 pr = ((const float2*)shpr)[ee];
          ushort4 v = *(const ushort4*)(alds + ee * 256 + ((tq ^ (ee & 31)) << 2));
          a0 += EX2(btof(v.x) * pr.x) * pr.y;
          a1 += EX2(btof(v.y) * pr.x) * pr.y;
          a2 += EX2(btof(v.z) * pr.x) * pr.y;
          a3 += EX2(btof(v.w) * pr.x) * pr.y;
        }
        ((float4*)(pC + es * 256))[tq] = make_float4(a0, a1, a2, a3);
      }
      __syncthreads();
      if (tid < 256) {
        float t0 = 0.f;
#pragma unroll
        for (int es = 0; es < 8; ++es) t0 += pC[es * 256 + tid];
        shtw[tid] = t0;
      }
      __syncthreads();
      // ctx partial (t-granules th*32..) -> pD (== pA, dead now)
      {
        const int sw = e & 31;
        float c0 = 0.f, c1 = 0.f;
#pragma unroll 8
        for (int q = 0; q < 32; ++q) {
          int g = th * 32 + q;
          ushort4 v = *(const ushort4*)(alds + e * 256 + ((g ^ sw) << 2));
          float4 tw4 = *(const float4*)(shtw + g * 4);
          c0 += tw4.x * btof(v.x) + tw4.y * btof(v.y);
          c1 += tw4.z * btof(v.z) + tw4.w * btof(v.w);
        }
        pD[th * 256 + e] = c0 + c1;
      }
      __syncthreads();
      // combine -> registers, barrier, then write through the alias
      float cv = 0.f;
      if (tid < 256) cv = pD[e] + pD[256 + e];
      __syncthreads();
      if (tid < 256) pc16[e] = f2bfbits(cv);
      __syncthreads();
      if (tid < 64)
        sysst64((ull*)(p.ctxb + (s & 3) * 8192 + b * 256) + tid, ((const ull*)pc16)[tid]);
      __syncthreads();
      if (tid == 0) sysst32(ctxdone + b * 16, (unsigned)(s + 1));
    }
  } else if (bid < 64) {
    // ============================ GRU path ============================
    const int dt = bid - 32;
    const int wv = tid >> 6;
    const bool act = wv < 6;
    const int l = tid & 63, lm = l & 15, lq = l >> 4;
    const int g = wv % 3, mt = wv / 3;
    const int am = mt * 16 + lm;
    const int brow = g * 512 + dt * 16 + lm;
    __hip_bfloat16* hA = (__hip_bfloat16*)smem;            // frag-major 32KB
    __hip_bfloat16* cA = (__hip_bfloat16*)(smem + 32768);  // frag-major 16KB
    float* pw = (float*)(smem + 49152);                    // [8][16][17]
    unsigned short* h16 = (unsigned short*)(smem + 57856); // [512]
    p0a_worker(p, (bid - 32) * 512 + tid);
    if (tid == 0) {
      while (sysld32(p.bar) != FLAGS_MAGIC) __builtin_amdgcn_s_sleep(1);
    }
    p0bar(p.bar);
    bf8 WH[16], WD[8], WC[8];
    if (act) {
#pragma unroll
      for (int kt = 0; kt < 16; ++kt) WH[kt] = ldfrag(p.whhb + brow * 512 + kt * 32 + lq * 8);
#pragma unroll
      for (int kt = 0; kt < 8; ++kt) WD[kt] = ldfrag(p.wihb + brow * 512 + kt * 32 + lq * 8);
#pragma unroll
      for (int kt = 0; kt < 8; ++kt) WC[kt] = ldfrag(p.wihb + brow * 512 + 256 + kt * 32 + lq * 8);
    }
    for (int s = 0; s < 64; ++s) {
      if (tid < 32) waitge(hdone + tid * 16, (unsigned)s);
      else if (tid < 34) waitge(meldone + (tid - 32) * 16, (s >= 4) ? (unsigned)(s - 3) : 0u);
      __syncthreads();
      stage_h_frag(hA, p.hbf + (s & 3) * 16384, tid);
      __syncthreads();
      f32x4 acc = {0.f, 0.f, 0.f, 0.f};
      f32x4 gi = {0.f, 0.f, 0.f, 0.f};
      if (act) {
#pragma unroll
        for (int kt = 0; kt < 16; ++kt) {
          bf8 a = ldfrag(hA + (mt * 16 + kt) * 512 + l * 8);
          acc = MFMA16(a, WH[kt], acc);
        }
        const __hip_bfloat16* seqp = p.seqb + s * 8192;
#pragma unroll
        for (int kt = 0; kt < 8; ++kt) {
          bf8 a = ldfrag(seqp + am * 256 + kt * 32 + lq * 8);
          gi = MFMA16(a, WD[kt], gi);
        }
      }
      if (tid < 32) waitge(ctxdone + tid * 16, (unsigned)(s + 1));
      __syncthreads();
      stage_c_frag(cA, p.ctxb + (s & 3) * 8192, tid);
      __syncthreads();
      if (act) {
#pragma unroll
        for (int kt = 0; kt < 8; ++kt) {
          bf8 a = ldfrag(cA + (mt * 8 + kt) * 512 + l * 8);
          gi = MFMA16(a, WC[kt], gi);
        }
        if (g < 2) {
#pragma unroll
          for (int r = 0; r < 4; ++r) pw[(wv * 16 + lq * 4 + r) * 17 + lm] = acc[r] + gi[r];
        } else {
#pragma unroll
          for (int r = 0; r < 4; ++r) pw[(wv * 16 + lq * 4 + r) * 17 + lm] = acc[r];
#pragma unroll
          for (int r = 0; r < 4; ++r) pw[((6 + mt) * 16 + lq * 4 + r) * 17 + lm] = gi[r];
        }
      }
      __syncthreads();
      {
        const int bb = tid >> 4, dl = tid & 15;
        const int mtb = bb >> 4, bl = bb & 15;
        float rg = sigm(pw[((mtb * 3 + 0) * 16 + bl) * 17 + dl]);
        float zg = sigm(pw[((mtb * 3 + 1) * 16 + bl) * 17 + dl]);
        float hn = pw[((mtb * 3 + 2) * 16 + bl) * 17 + dl];
        float inn = pw[((6 + mtb) * 16 + bl) * 17 + dl];
        float nn = tanhfast(fmaf(rg, hn, inn));
        const int d = dt * 16 + dl;
        // old h from fragment-major hA
        float ho = btof(((unsigned short*)hA)[((bb >> 4) * 16 + (d >> 5)) * 512 +
                                              (((d >> 3) & 3) * 16 + (bb & 15)) * 8 +
                                              (d & 7)]);
        float hnew = fmaxf(0.0f, fmaf(zg, ho - nn, nn));
        h16[bb * 16 + dl] = f2bfbits(hnew);
      }
      __syncthreads();
      if (tid < 256) {
        const int bb2 = tid >> 3, dp = tid & 7;
        unsigned v = (unsigned)h16[bb2 * 16 + dp * 2] |
                     ((unsigned)h16[bb2 * 16 + dp * 2 + 1] << 16);
        sysst32((unsigned*)(p.hbf + ((s + 1) & 3) * 16384) + bb2 * 256 + dt * 8 + dp, v);
      }
      __syncthreads();
      if (tid == 0) sysst32(hdone + dt * 16, (unsigned)(s + 1));
    }
  } else {
    // ============================ MEL path ============================
    const int mt = bid - 64;
    const int wv = tid >> 6;
    const bool act = wv < 6;
    const int l = tid & 63, lm = l & 15, lq = l >> 4;
    const int nt = wv;
    const int am = mt * 16 + lm, bn = nt * 16 + lm;
    __hip_bfloat16* hA = (__hip_bfloat16*)smem;
    __hip_bfloat16* cA = (__hip_bfloat16*)(smem + 32768);
    p0a_worker(p, (bid - 32) * 512 + tid);
    if (tid == 0) {
      while (sysld32(p.bar) != FLAGS_MAGIC) __builtin_amdgcn_s_sleep(1);
    }
    p0bar(p.bar);
    bf8 WM[24];
    float bias = 0.f;
    if (act) {
#pragma unroll
      for (int kt = 0; kt < 24; ++kt) WM[kt] = ldfrag(p.wmelgb + bn * 768 + kt * 32 + lq * 8);
      bias = (bn < 80) ? p.bmel[bn] : ((bn == 80) ? p.bgate[0] : 0.f);
    }
    for (int tau = 0; tau < 64; ++tau) {
      if (tid < 32) waitge(hdone + tid * 16, (unsigned)(tau + 1));
      __syncthreads();
      stage_h_frag(hA, p.hbf + ((tau + 1) & 3) * 16384, tid);
      stage_c_frag(cA, p.ctxb + (tau & 3) * 8192, tid);
      __syncthreads();
      if (act) {
        f32x4 acc = {0.f, 0.f, 0.f, 0.f};
#pragma unroll
        for (int kt = 0; kt < 24; ++kt) {
          bf8 a = (kt < 8) ? ldfrag(cA + (mt * 8 + kt) * 512 + l * 8)
                           : ldfrag(hA + (mt * 16 + (kt - 8)) * 512 + l * 8);
          acc = MFMA16(a, WM[kt], acc);
        }
#pragma unroll
        for (int r = 0; r < 4; ++r) {
          int bb = mt * 16 + lq * 4 + r;
          float v = acc[r] + bias;
          if (bn < 80)
            p.out[bb * 5120 + bn * 64 + tau] = v;
          else if (bn == 80)
            p.out[163840 + bb * 64 + tau] = v;
        }
      }
      __syncthreads();
      if (tid == 0) sysst32(meldone + mt * 16, (unsigned)(tau + 1));
    }
  }
}

extern "C" void kernel_launch(void* const* d_in, const int* in_sizes, int n_in,
                              void* d_out, int out_size, void* d_ws, size_t ws_size,
                              hipStream_t stream) {
  Params P;
  P.dec = (const float*)d_in[0];
  P.ali = (const float*)d_in[1];
  P.watt = (const float*)d_in[2];
  P.wih = (const float*)d_in[3];
  P.whh = (const float*)d_in[4];
  P.wmel = (const float*)d_in[5];
  P.bmel = (const float*)d_in[6];
  P.wgate = (const float*)d_in[7];
  P.bgate = (const float*)d_in[8];
  P.out = (float*)d_out;

  char* w = (char*)d_ws;
  size_t o = 0;
  auto nxt = [&](size_t b) {
    char* r = w + o;
    o += (b + 255) & ~(size_t)255;
    return r;
  };
  P.bar = (unsigned*)nxt(8192);
  P.wihb = (__hip_bfloat16*)nxt(1536 * 512 * 2);
  P.whhb = (__hip_bfloat16*)nxt(1536 * 512 * 2);
  P.wmelgb = (__hip_bfloat16*)nxt(96 * 768 * 2);
  P.seqb = (__hip_bfloat16*)nxt(64 * 32 * 256 * 2);
  P.hbf = (__hip_bfloat16*)nxt(4 * 32 * 512 * 2);
  P.ctxb = (__hip_bfloat16*)nxt(4 * 32 * 256 * 2);
  P.wattp = (unsigned*)nxt(256 * 256 * 4);

  (void)hipFuncSetAttribute((const void*)rdec_kernel,
                            hipFuncAttributeMaxDynamicSharedMemorySize, SMEM_BYTES);

  void* args[] = {&P};
  hipError_t err = hipLaunchCooperativeKernel((void*)rdec_kernel, dim3(66), dim3(512),
                                              args, SMEM_BYTES, stream);
  if (err != hipSuccess) {
    rdec_kernel<<<dim3(66), dim3(512), SMEM_BYTES, stream>>>(P);
  }
}

// Round 10
// 1292.346 us; speedup vs baseline: 1.4848x; 1.2436x over previous
//
#include <hip/hip_runtime.h>
#include <hip/hip_bf16.h>

// ============================================================================
// RecurrentDecoder v10: 98-block persistent kernel, flag dataflow.
// v9 -> v10: attention split 2 blocks/batch by t-half (64 att blocks).
//  - exp values u=exp2(a*p) computed ONCE per (e,t) and cached in LDS (bf16);
//    tw pass is pure FMA. exp2 count per block-step: 131072 -> 32768.
//  - cross-half softmax denominator via paired 1KB Z-exchange (zbuf+zdone).
//  - partial ctx halves published separately; GRU/mel consume [ctxA;ctxB] as
//    K=512 MFMA with W-row-duplication (WC[kt&7]) -- no combine handoff.
// GRU blocks 64..95 (d-slice, weights in VGPRs), mel 96..97.
// ============================================================================

#define LOG2E 1.4426950408889634f
#define FLAGS_MAGIC 0x13572468u
#define SMEM_BYTES 146944
#define NBLK 98

typedef __attribute__((ext_vector_type(8))) short bf8;
typedef __attribute__((ext_vector_type(4))) float f32x4;
typedef __attribute__((ext_vector_type(4))) unsigned u32x4;
typedef unsigned long long ull;

#define EX2(x) exp2f(x)
#define MFMA16(a, b, c) __builtin_amdgcn_mfma_f32_16x16x32_bf16(a, b, c, 0, 0, 0)

struct Params {
  const float* dec;
  const float* ali;
  const float* watt;
  const float* wih;
  const float* whh;
  const float* wmel;
  const float* bmel;
  const float* wgate;
  const float* bgate;
  float* out;
  unsigned* bar;  // [0]=magic [16]=p0cnt [32+16i]=hdone(32) [544+16j]=ctxdone(64)
                  // [1568+16m]=meldone(2) [1600+16k]=zdone(64)
  __hip_bfloat16* wihb;    // [1536][512]
  __hip_bfloat16* whhb;    // [1536][512]
  __hip_bfloat16* wmelgb;  // [96][768]
  __hip_bfloat16* seqb;    // [64][32][256]
  __hip_bfloat16* hbf;     // ring [4][32][512]
  __hip_bfloat16* ctxb;    // ring [4][64][256]  (hb = hf*32+b)
  float* zbuf;             // ring [4][64][256] fp32 partial denominators
  unsigned* wattp;         // [256][256] packed bf16 pairs of W_att^T
};

__device__ __forceinline__ bf8 ldfrag(const __hip_bfloat16* p) { return *(const bf8*)p; }
__device__ __forceinline__ float sigm(float x) { return 1.0f / (1.0f + EX2(-x * LOG2E)); }
__device__ __forceinline__ float tanhfast(float x) {
  x = fminf(fmaxf(x, -15.0f), 15.0f);
  float e = EX2(x * (2.0f * LOG2E));
  return (e - 1.0f) / (e + 1.0f);
}
__device__ __forceinline__ float btof(unsigned v) { return __uint_as_float(v << 16); }
__device__ __forceinline__ unsigned short f2bfbits(float x) {
  __hip_bfloat16 h = __float2bfloat16(x);
  return *(unsigned short*)&h;
}
__device__ __forceinline__ unsigned sysld32(const unsigned* p) {
  return __hip_atomic_load(p, __ATOMIC_RELAXED, __HIP_MEMORY_SCOPE_SYSTEM);
}
__device__ __forceinline__ ull sysld64(const ull* p) {
  return __hip_atomic_load(p, __ATOMIC_RELAXED, __HIP_MEMORY_SCOPE_SYSTEM);
}
__device__ __forceinline__ void sysst32(unsigned* p, unsigned v) {
  __hip_atomic_store(p, v, __ATOMIC_RELAXED, __HIP_MEMORY_SCOPE_SYSTEM);
}
__device__ __forceinline__ void sysst64(ull* p, ull v) {
  __hip_atomic_store(p, v, __ATOMIC_RELAXED, __HIP_MEMORY_SCOPE_SYSTEM);
}
__device__ __forceinline__ u32x4 sysld16(const void* p0) {
  u32x4 a;
  asm volatile("global_load_dwordx4 %0, %1, off sc0 sc1\n\ts_waitcnt vmcnt(0)"
               : "=&v"(a) : "v"(p0) : "memory");
  return a;
}
__device__ __forceinline__ void sysld16x4(u32x4* d0, u32x4* d1, u32x4* d2, u32x4* d3,
                                          const void* p0, const void* p1,
                                          const void* p2, const void* p3) {
  u32x4 a, b, c, d;
  asm volatile(
      "global_load_dwordx4 %0, %4, off sc0 sc1\n\t"
      "global_load_dwordx4 %1, %5, off sc0 sc1\n\t"
      "global_load_dwordx4 %2, %6, off sc0 sc1\n\t"
      "global_load_dwordx4 %3, %7, off sc0 sc1\n\t"
      "s_waitcnt vmcnt(0)"
      : "=&v"(a), "=&v"(b), "=&v"(c), "=&v"(d)
      : "v"(p0), "v"(p1), "v"(p2), "v"(p3)
      : "memory");
  *d0 = a; *d1 = b; *d2 = c; *d3 = d;
}
__device__ __forceinline__ void waitge(unsigned* w, unsigned tgt) {
  while (sysld32(w) < tgt) __builtin_amdgcn_s_sleep(1);
}

__device__ __forceinline__ void p0bar(unsigned* bar) {
  __syncthreads();
  if (threadIdx.x == 0) {
    __builtin_amdgcn_fence(__ATOMIC_RELEASE, "agent");
    __hip_atomic_fetch_add(bar + 16, 1u, __ATOMIC_RELAXED, __HIP_MEMORY_SCOPE_SYSTEM);
    while (sysld32(bar + 16) < (unsigned)NBLK) __builtin_amdgcn_s_sleep(1);
    __builtin_amdgcn_fence(__ATOMIC_ACQUIRE, "agent");
  }
  __syncthreads();
}

// P0 conversion work for blocks 64..97 (wid in [0, 34*512))
__device__ __forceinline__ void p0a_worker(const Params& p, int wid) {
  for (int i = wid; i < 2252800; i += 17408) {
    if (i < 786432) {
      p.wihb[i] = __float2bfloat16(p.wih[i]);
    } else if (i < 1572864) {
      int j = i - 786432;
      p.whhb[j] = __float2bfloat16(p.whh[j]);
    } else if (i < 2097152) {
      int j = i - 1572864;
      int s = j >> 13;
      p.seqb[j] = (s == 0) ? __float2bfloat16(0.0f) : __float2bfloat16(p.dec[j - 8192]);
    } else if (i < 2170880) {
      int j = i - 2097152;
      int r = j / 768, c = j - r * 768;
      float v = (r < 80) ? p.wmel[j] : ((r == 80) ? p.wgate[c] : 0.0f);
      p.wmelgb[j] = __float2bfloat16(v);
    } else if (i < 2236416) {
      int j = i - 2170880;
      int kp = j >> 8, e = j & 255;
      unsigned lo = f2bfbits(p.watt[e * 512 + 2 * kp]);
      unsigned hi = f2bfbits(p.watt[e * 512 + 2 * kp + 1]);
      p.wattp[j] = lo | (hi << 16);
    } else {
      int j = i - 2236416;
      p.hbf[j] = __float2bfloat16(0.0f);  // h ring slot 0 = h(0) = 0
    }
  }
}

// Stage h[32][512] (row-major, coherent) into fragment-major LDS (32 sections).
__device__ __forceinline__ void stage_h_frag(__hip_bfloat16* hA,
                                             const __hip_bfloat16* hsrc, int tid) {
  const int lm = tid & 15, lq = (tid >> 4) & 3, wq = tid >> 6;
  const int dst_in = (lq * 16 + lm) * 8;
  const int i0 = wq, i1 = 8 + wq, i2 = 16 + wq, i3 = 24 + wq;
  auto soff = [&](int idx) {
    return ((idx >> 4) * 16 + lm) * 512 + (idx & 15) * 32 + lq * 8;
  };
  u32x4 a, b, c, d;
  sysld16x4(&a, &b, &c, &d, hsrc + soff(i0), hsrc + soff(i1), hsrc + soff(i2),
            hsrc + soff(i3));
  u32x4* dst = (u32x4*)hA;
  dst[(i0 * 512 + dst_in) >> 3] = a;
  dst[(i1 * 512 + dst_in) >> 3] = b;
  dst[(i2 * 512 + dst_in) >> 3] = c;
  dst[(i3 * 512 + dst_in) >> 3] = d;
}
// Stage concat-ctx [b, k=hf*256+e] (src ctxb slot: [64][256], hb=hf*32+b) into
// fragment-major LDS (32 sections over K=512).
__device__ __forceinline__ void stage_c2(__hip_bfloat16* cA,
                                         const __hip_bfloat16* csrc, int tid) {
  const int lm = tid & 15, lq = (tid >> 4) & 3, wq = tid >> 6;
  const int dst_in = (lq * 16 + lm) * 8;
  const int i0 = wq, i1 = 8 + wq, i2 = 16 + wq, i3 = 24 + wq;
  auto soff = [&](int idx) {
    int bb = (idx >> 4) * 16 + lm;
    int k = (idx & 15) * 32 + lq * 8;
    return ((k >> 8) * 32 + bb) * 256 + (k & 255);
  };
  u32x4 a, b, c, d;
  sysld16x4(&a, &b, &c, &d, csrc + soff(i0), csrc + soff(i1), csrc + soff(i2),
            csrc + soff(i3));
  u32x4* dst = (u32x4*)cA;
  dst[(i0 * 512 + dst_in) >> 3] = a;
  dst[(i1 * 512 + dst_in) >> 3] = b;
  dst[(i2 * 512 + dst_in) >> 3] = c;
  dst[(i3 * 512 + dst_in) >> 3] = d;
}

__global__ void __launch_bounds__(512, 1) rdec_kernel(Params p) {
  const int tid = threadIdx.x;
  const int bid = blockIdx.x;
  extern __shared__ char smem[];
  unsigned* hdone = p.bar + 32;      // 32 flags
  unsigned* ctxdone = p.bar + 544;   // 64 flags
  unsigned* meldone = p.bar + 1568;  // 2 flags
  unsigned* zdone = p.bar + 1600;    // 64 flags

  if (bid == 0) {
    for (int i = 1 + tid; i < 2624; i += 512) sysst32(p.bar + i, 0u);
    __syncthreads();
    if (tid == 0) sysst32(p.bar, FLAGS_MAGIC);
  }

  if (bid < 64) {
    // ============================ ATT path (b, t-half hf) ============================
    const int b = bid >> 1, hf = bid & 1, hb = hf * 32 + b;
    unsigned short* alds = (unsigned short*)smem;            // [256e][128t] swizzled
    unsigned short* ubuf = (unsigned short*)(smem + 65536);  // [256e][128t] swizzled
    float* fb = (float*)(smem + 131072);
    float* shh = fb;          // 512
    float* pA = fb + 512;     // 512 (proj partials; later my-Zpart; later pc16)
    float* pB = fb + 1024;    // 512 (den partials; later partner-Z; later ctx partials)
    float* shz = fb + 1536;   // 256
    float* shtw = fb + 1792;  // 128
    float* pC = fb + 1920;    // 2048 ([16][128])
    unsigned short* pc16 = (unsigned short*)pA;
    const int e = tid & 255, th = tid >> 8;
    const int sw = e & 31;

    // P0: my t-half of ali -> swizzled LDS
    for (int i = tid; i < 32768; i += 512) {
      int tl = i >> 8, ee = i & 255;
      alds[ee * 128 + ((((tl >> 2) ^ (ee & 31))) << 2) + (tl & 3)] =
          f2bfbits(p.ali[(hf * 128 + tl) * 8192 + b * 256 + ee]);
    }
    if (tid == 0) {
      while (sysld32(p.bar) != FLAGS_MAGIC) __builtin_amdgcn_s_sleep(1);
    }
    p0bar(p.bar);
    unsigned wr[128];
#pragma unroll
    for (int i = 0; i < 128; ++i) wr[i] = p.wattp[(th * 128 + i) * 256 + e];

    for (int s = 0; s < 64; ++s) {
      if (tid < 32) waitge(hdone + tid * 16, (unsigned)s);
      else if (tid < 34) waitge(meldone + (tid - 32) * 16, (s >= 4) ? (unsigned)(s - 3) : 0u);
      __syncthreads();
      // h(s)[b,:] -> shh fp32
      if (tid < 128) {
        ull w = sysld64((const ull*)(p.hbf + (s & 3) * 16384 + b * 512) + tid);
        shh[tid * 4 + 0] = btof((unsigned)(w & 0xffff));
        shh[tid * 4 + 1] = btof((unsigned)((w >> 16) & 0xffff));
        shh[tid * 4 + 2] = btof((unsigned)((w >> 32) & 0xffff));
        shh[tid * 4 + 3] = btof((unsigned)((w >> 48) & 0xffff));
      }
      __syncthreads();
      // proj partials (k-split by th)
      {
        float acc = 0.f;
        const float2* h2 = (const float2*)shh;
#pragma unroll
        for (int i = 0; i < 128; ++i) {
          unsigned w = wr[i];
          float2 hv = h2[th * 128 + i];
          acc = fmaf(__uint_as_float(w << 16), hv.x, acc);
          acc = fmaf(__uint_as_float(w & 0xffff0000u), hv.y, acc);
        }
        pA[th * 256 + e] = acc;
      }
      __syncthreads();
      // den: compute u once (cache to ubuf), accumulate Z partial
      {
        const float p2 = (pA[e] + pA[256 + e]) * LOG2E;
        float dsum = 0.f;
#pragma unroll 4
        for (int q = 0; q < 16; ++q) {
          int g = th * 16 + q;
          int off = e * 128 + ((g ^ sw) << 2);
          ushort4 v = *(const ushort4*)(alds + off);
          float u0 = EX2(btof(v.x) * p2);
          float u1 = EX2(btof(v.y) * p2);
          float u2 = EX2(btof(v.z) * p2);
          float u3 = EX2(btof(v.w) * p2);
          dsum += (u0 + u1) + (u2 + u3);
          ull w = (ull)f2bfbits(u0) | ((ull)f2bfbits(u1) << 16) |
                  ((ull)f2bfbits(u2) << 32) | ((ull)f2bfbits(u3) << 48);
          *(ull*)(ubuf + off) = w;
        }
        pB[th * 256 + e] = dsum;
      }
      __syncthreads();
      if (tid < 256) pA[e] = pB[e] + pB[256 + e];  // my Z partial (pA dead)
      __syncthreads();
      // publish my Zpart (1KB), flag, poll partner, read partner Zpart
      if (tid < 64) {
        ull* zs = (ull*)(p.zbuf + ((s & 3) * 64 + hb) * 256);
        const ull* za = (const ull*)pA;
        sysst64(zs + tid * 2, za[tid * 2]);
        sysst64(zs + tid * 2 + 1, za[tid * 2 + 1]);
      }
      __syncthreads();
      if (tid == 0) {
        sysst32(zdone + hb * 16, (unsigned)(s + 1));
        waitge(zdone + (hb ^ 32) * 16, (unsigned)(s + 1));
      }
      __syncthreads();
      if (tid < 64) {
        u32x4 v = sysld16((const char*)(p.zbuf + ((s & 3) * 64 + (hb ^ 32)) * 256) + tid * 16);
        ((u32x4*)pB)[tid] = v;
      }
      __syncthreads();
      if (tid < 256) shz[e] = 1.0f / (pA[e] + pB[e]);
      __syncthreads();
      // tw partials: pure FMA over cached u (e-split 16-way)
      {
        const int es = tid >> 5, g = tid & 31;
        float a0 = 0.f, a1 = 0.f, a2 = 0.f, a3 = 0.f;
#pragma unroll 4
        for (int j = 0; j < 16; ++j) {
          int ee = es * 16 + j;
          ushort4 v = *(const ushort4*)(ubuf + ee * 128 + ((g ^ (ee & 31)) << 2));
          float rz = shz[ee];
          a0 = fmaf(btof(v.x), rz, a0);
          a1 = fmaf(btof(v.y), rz, a1);
          a2 = fmaf(btof(v.z), rz, a2);
          a3 = fmaf(btof(v.w), rz, a3);
        }
        ((float4*)(pC + es * 128))[g] = make_float4(a0, a1, a2, a3);
      }
      __syncthreads();
      if (tid < 128) {
        float t0 = 0.f;
#pragma unroll
        for (int es = 0; es < 16; ++es) t0 += pC[es * 128 + tid];
        shtw[tid] = t0;
      }
      __syncthreads();
      // partial ctx over my t-half
      {
        float c0 = 0.f, c1 = 0.f;
#pragma unroll 4
        for (int q = 0; q < 16; ++q) {
          int g = th * 16 + q;
          ushort4 v = *(const ushort4*)(alds + e * 128 + ((g ^ sw) << 2));
          float4 t4 = *(const float4*)(shtw + g * 4);
          c0 += t4.x * btof(v.x) + t4.y * btof(v.y);
          c1 += t4.z * btof(v.z) + t4.w * btof(v.w);
        }
        pB[th * 256 + e] = c0 + c1;
      }
      __syncthreads();
      float cv = 0.f;
      if (tid < 256) cv = pB[e] + pB[256 + e];
      __syncthreads();
      if (tid < 256) pc16[e] = f2bfbits(cv);
      __syncthreads();
      if (tid < 32) {
        ull* cs = (ull*)(p.ctxb + ((s & 3) * 64 + hb) * 256);
        const ull* ca = (const ull*)pc16;
        sysst64(cs + tid * 2, ca[tid * 2]);
        sysst64(cs + tid * 2 + 1, ca[tid * 2 + 1]);
      }
      __syncthreads();
      if (tid == 0) sysst32(ctxdone + hb * 16, (unsigned)(s + 1));
    }
  } else if (bid < 96) {
    // ============================ GRU path ============================
    const int dt = bid - 64;
    const int wv = tid >> 6;
    const bool act = wv < 6;
    const int l = tid & 63, lm = l & 15, lq = l >> 4;
    const int g = wv % 3, mt = wv / 3;
    const int am = mt * 16 + lm;
    const int brow = g * 512 + dt * 16 + lm;
    __hip_bfloat16* hA = (__hip_bfloat16*)smem;             // frag-major 32KB
    __hip_bfloat16* cA = (__hip_bfloat16*)(smem + 32768);   // frag-major 32KB (K=512)
    float* pw = (float*)(smem + 65536);                     // [8][16][17]
    unsigned short* h16 = (unsigned short*)(smem + 74240);  // [512]
    p0a_worker(p, (bid - 64) * 512 + tid);
    if (tid == 0) {
      while (sysld32(p.bar) != FLAGS_MAGIC) __builtin_amdgcn_s_sleep(1);
    }
    p0bar(p.bar);
    bf8 WH[16], WD[8], WC[8];
    if (act) {
#pragma unroll
      for (int kt = 0; kt < 16; ++kt) WH[kt] = ldfrag(p.whhb + brow * 512 + kt * 32 + lq * 8);
#pragma unroll
      for (int kt = 0; kt < 8; ++kt) WD[kt] = ldfrag(p.wihb + brow * 512 + kt * 32 + lq * 8);
#pragma unroll
      for (int kt = 0; kt < 8; ++kt) WC[kt] = ldfrag(p.wihb + brow * 512 + 256 + kt * 32 + lq * 8);
    }
    for (int s = 0; s < 64; ++s) {
      if (tid < 32) waitge(hdone + tid * 16, (unsigned)s);
      else if (tid < 34) waitge(meldone + (tid - 32) * 16, (s >= 4) ? (unsigned)(s - 3) : 0u);
      __syncthreads();
      stage_h_frag(hA, p.hbf + (s & 3) * 16384, tid);
      __syncthreads();
      f32x4 acc = {0.f, 0.f, 0.f, 0.f};
      f32x4 gi = {0.f, 0.f, 0.f, 0.f};
      if (act) {
#pragma unroll
        for (int kt = 0; kt < 16; ++kt) {
          bf8 a = ldfrag(hA + (mt * 16 + kt) * 512 + l * 8);
          acc = MFMA16(a, WH[kt], acc);
        }
        const __hip_bfloat16* seqp = p.seqb + s * 8192;
#pragma unroll
        for (int kt = 0; kt < 8; ++kt) {
          bf8 a = ldfrag(seqp + am * 256 + kt * 32 + lq * 8);
          gi = MFMA16(a, WD[kt], gi);
        }
      }
      if (tid < 64) waitge(ctxdone + tid * 16, (unsigned)(s + 1));
      __syncthreads();
      stage_c2(cA, p.ctxb + (s & 3) * 16384, tid);
      __syncthreads();
      if (act) {
        // gi_ctx over K=512 concat halves with duplicated W rows
#pragma unroll
        for (int kt = 0; kt < 16; ++kt) {
          bf8 a = ldfrag(cA + (mt * 16 + kt) * 512 + l * 8);
          gi = MFMA16(a, WC[kt & 7], gi);
        }
        if (g < 2) {
#pragma unroll
          for (int r = 0; r < 4; ++r) pw[(wv * 16 + lq * 4 + r) * 17 + lm] = acc[r] + gi[r];
        } else {
#pragma unroll
          for (int r = 0; r < 4; ++r) pw[(wv * 16 + lq * 4 + r) * 17 + lm] = acc[r];
#pragma unroll
          for (int r = 0; r < 4; ++r) pw[((6 + mt) * 16 + lq * 4 + r) * 17 + lm] = gi[r];
        }
      }
      __syncthreads();
      {
        const int bb = tid >> 4, dl = tid & 15;
        const int mtb = bb >> 4, bl = bb & 15;
        float rg = sigm(pw[((mtb * 3 + 0) * 16 + bl) * 17 + dl]);
        float zg = sigm(pw[((mtb * 3 + 1) * 16 + bl) * 17 + dl]);
        float hn = pw[((mtb * 3 + 2) * 16 + bl) * 17 + dl];
        float inn = pw[((6 + mtb) * 16 + bl) * 17 + dl];
        float nn = tanhfast(fmaf(rg, hn, inn));
        const int d = dt * 16 + dl;
        float ho = btof(((unsigned short*)hA)[((bb >> 4) * 16 + (d >> 5)) * 512 +
                                              (((d >> 3) & 3) * 16 + (bb & 15)) * 8 +
                                              (d & 7)]);
        float hnew = fmaxf(0.0f, fmaf(zg, ho - nn, nn));
        h16[bb * 16 + dl] = f2bfbits(hnew);
      }
      __syncthreads();
      if (tid < 256) {
        const int bb2 = tid >> 3, dp = tid & 7;
        unsigned v = (unsigned)h16[bb2 * 16 + dp * 2] |
                     ((unsigned)h16[bb2 * 16 + dp * 2 + 1] << 16);
        sysst32((unsigned*)(p.hbf + ((s + 1) & 3) * 16384) + bb2 * 256 + dt * 8 + dp, v);
      }
      __syncthreads();
      if (tid == 0) sysst32(hdone + dt * 16, (unsigned)(s + 1));
    }
  } else {
    // ============================ MEL path ============================
    const int mt = bid - 96;  // batch half
    const int wv = tid >> 6;
    const bool act = wv < 6;
    const int l = tid & 63, lm = l & 15, lq = l >> 4;
    const int nt = wv;
    const int bn = nt * 16 + lm;
    __hip_bfloat16* hA = (__hip_bfloat16*)smem;
    __hip_bfloat16* cA = (__hip_bfloat16*)(smem + 32768);
    p0a_worker(p, (bid - 64) * 512 + tid);
    if (tid == 0) {
      while (sysld32(p.bar) != FLAGS_MAGIC) __builtin_amdgcn_s_sleep(1);
    }
    p0bar(p.bar);
    bf8 WMC[8], WMH[16];
    float bias = 0.f;
    if (act) {
#pragma unroll
      for (int kt = 0; kt < 8; ++kt) WMC[kt] = ldfrag(p.wmelgb + bn * 768 + kt * 32 + lq * 8);
#pragma unroll
      for (int kt = 0; kt < 16; ++kt)
        WMH[kt] = ldfrag(p.wmelgb + bn * 768 + 256 + kt * 32 + lq * 8);
      bias = (bn < 80) ? p.bmel[bn] : ((bn == 80) ? p.bgate[0] : 0.f);
    }
    for (int tau = 0; tau < 64; ++tau) {
      if (tid < 32) waitge(hdone + tid * 16, (unsigned)(tau + 1));
      else if (tid >= 64 && tid < 128) waitge(ctxdone + (tid - 64) * 16, (unsigned)(tau + 1));
      __syncthreads();
      stage_h_frag(hA, p.hbf + ((tau + 1) & 3) * 16384, tid);
      stage_c2(cA, p.ctxb + (tau & 3) * 16384, tid);
      __syncthreads();
      if (act) {
        f32x4 acc = {0.f, 0.f, 0.f, 0.f};
#pragma unroll
        for (int kt = 0; kt < 32; ++kt) {
          bf8 a = (kt < 16) ? ldfrag(cA + (mt * 16 + kt) * 512 + l * 8)
                            : ldfrag(hA + (mt * 16 + (kt - 16)) * 512 + l * 8);
          bf8 bb2 = (kt < 16) ? WMC[kt & 7] : WMH[kt - 16];
          acc = MFMA16(a, bb2, acc);
        }
#pragma unroll
        for (int r = 0; r < 4; ++r) {
          int bb = mt * 16 + lq * 4 + r;
          float v = acc[r] + bias;
          if (bn < 80)
            p.out[bb * 5120 + bn * 64 + tau] = v;
          else if (bn == 80)
            p.out[163840 + bb * 64 + tau] = v;
        }
      }
      __syncthreads();
      if (tid == 0) sysst32(meldone + mt * 16, (unsigned)(tau + 1));
    }
  }
}

extern "C" void kernel_launch(void* const* d_in, const int* in_sizes, int n_in,
                              void* d_out, int out_size, void* d_ws, size_t ws_size,
                              hipStream_t stream) {
  Params P;
  P.dec = (const float*)d_in[0];
  P.ali = (const float*)d_in[1];
  P.watt = (const float*)d_in[2];
  P.wih = (const float*)d_in[3];
  P.whh = (const float*)d_in[4];
  P.wmel = (const float*)d_in[5];
  P.bmel = (const float*)d_in[6];
  P.wgate = (const float*)d_in[7];
  P.bgate = (const float*)d_in[8];
  P.out = (float*)d_out;

  char* w = (char*)d_ws;
  size_t o = 0;
  auto nxt = [&](size_t b) {
    char* r = w + o;
    o += (b + 255) & ~(size_t)255;
    return r;
  };
  P.bar = (unsigned*)nxt(16384);
  P.wihb = (__hip_bfloat16*)nxt(1536 * 512 * 2);
  P.whhb = (__hip_bfloat16*)nxt(1536 * 512 * 2);
  P.wmelgb = (__hip_bfloat16*)nxt(96 * 768 * 2);
  P.seqb = (__hip_bfloat16*)nxt(64 * 32 * 256 * 2);
  P.hbf = (__hip_bfloat16*)nxt(4 * 32 * 512 * 2);
  P.ctxb = (__hip_bfloat16*)nxt(4 * 64 * 256 * 2);
  P.zbuf = (float*)nxt(4 * 64 * 256 * 4);
  P.wattp = (unsigned*)nxt(256 * 256 * 4);

  (void)hipFuncSetAttribute((const void*)rdec_kernel,
                            hipFuncAttributeMaxDynamicSharedMemorySize, SMEM_BYTES);

  void* args[] = {&P};
  hipError_t err = hipLaunchCooperativeKernel((void*)rdec_kernel, dim3(NBLK), dim3(512),
                                              args, SMEM_BYTES, stream);
  if (err != hipSuccess) {
    rdec_kernel<<<dim3(NBLK), dim3(512), SMEM_BYTES, stream>>>(P);
  }
}